// Round 9
// baseline (146.264 us; speedup 1.0000x reference)
//
#include <hip/hip_runtime.h>
#include <math.h>

#define DD 384
#define HD 1024
#define CD 256
#define NS 765        // 2*DD-1 shifts
#define NITER 4
#define NROWS 256     // B*T
#define TEMPER_F 10.0f
#define EPSF 1e-6f
#define CUTF 1e-10f

typedef unsigned long long u64;
typedef unsigned int u32;

// monotone float->uint (ascending)
__device__ __forceinline__ u32 flipf(float f) {
    u32 u = __float_as_uint(f);
    return u ^ ((u32)((int)u >> 31) | 0x80000000u);
}
// inverse, where s = ~flip(v)
__device__ __forceinline__ float unflipf(u32 s) {
    u32 fl = ~s;
    u32 u = (fl & 0x80000000u) ? (fl ^ 0x80000000u) : ~fl;
    return __uint_as_float(u);
}
__device__ __forceinline__ u64 shflx64(u64 v, int m) {
    int lo = __shfl_xor((int)(u32)v, m, 64);
    int hi = __shfl_xor((int)(u32)(v >> 32), m, 64);
    return ((u64)(u32)hi << 32) | (u32)lo;
}

// ---------------- 1) prep: per-row theta / attn / x_ele + y-count ----------------
__global__ __launch_bounds__(512) void prep_kernel(
    const float* __restrict__ x, const float* __restrict__ y,
    float* __restrict__ xe_g, int* __restrict__ ycnt)
{
    const int row  = blockIdx.x;
    const int tid  = threadIdx.x;
    const int lane = tid & 63;
    const int wid  = tid >> 6;

    __shared__ __align__(16) float xpad[1152];
    __shared__ __align__(16) float yr[DD];
    __shared__ float xa[DD];
    __shared__ float wred[8];
    __shared__ int   wredi[8];
    __shared__ float wredn[8];
    __shared__ float s_sc[4];
    __shared__ int   s_theta;

    const float* xrow = x + row * DD;
    const float* yrow = y + row * DD;

    for (int i = tid; i < 1152; i += 512)
        xpad[i] = (i >= DD - 1 && i < 2 * DD - 1) ? xrow[i - (DD - 1)] : 0.f;
    if (tid < DD) yr[tid] = yrow[tid];
    __syncthreads();

    // qn = ||y||
    if (tid < DD) {
        float p = yr[tid] * yr[tid];
        for (int o = 32; o; o >>= 1) p += __shfl_xor(p, o, 64);
        if (lane == 0) wred[wid] = p;
    }
    __syncthreads();
    if (tid == 0) {
        float s = 0.f;
        for (int w = 0; w < 6; ++w) s += wred[w];
        s_sc[0] = sqrtf(s);
    }
    __syncthreads();
    const float qn = s_sc[0];

    // sim argmax: threads 0..191, 4 consecutive shifts each, sliding window
    float bv = -INFINITY; int bs = 0x7fffffff; float bn = 0.f;
    if (tid < 192) {
        const float4* xp4 = (const float4*)xpad;
        const float4* yp4 = (const float4*)yr;
        float4 A = xp4[tid];
        const float f0 = A.x * A.x, f1 = A.y * A.y, f2 = A.z * A.z;
        float d0 = 0.f, d1 = 0.f, d2 = 0.f, d3 = 0.f, n0 = 0.f;
#pragma unroll 4
        for (int jc = 0; jc < 96; ++jc) {
            float4 B = xp4[tid + jc + 1];
            float4 Y = yp4[jc];
            d0 += A.x * Y.x; d0 += A.y * Y.y; d0 += A.z * Y.z; d0 += A.w * Y.w;
            d1 += A.y * Y.x; d1 += A.z * Y.y; d1 += A.w * Y.z; d1 += B.x * Y.w;
            d2 += A.z * Y.x; d2 += A.w * Y.y; d2 += B.x * Y.z; d2 += B.y * Y.w;
            d3 += A.w * Y.x; d3 += B.x * Y.y; d3 += B.y * Y.z; d3 += B.z * Y.w;
            n0 += A.x * A.x; n0 += A.y * A.y; n0 += A.z * A.z; n0 += A.w * A.w;
            A = B;
        }
        const float n1 = n0 - f0 + A.x * A.x;
        const float n2 = n1 - f1 + A.y * A.y;
        const float n3 = n2 - f2 + A.z * A.z;
        const int s0 = 4 * tid;
        float sim0 = d0 / (qn * sqrtf(n0) + EPSF);
        float sim1 = d1 / (qn * sqrtf(n1) + EPSF);
        float sim2 = d2 / (qn * sqrtf(n2) + EPSF);
        float sim3 = d3 / (qn * sqrtf(n3) + EPSF);
        bv = sim0; bs = s0; bn = n0;
        if (s0 + 1 < NS && sim1 > bv) { bv = sim1; bs = s0 + 1; bn = n1; }
        if (s0 + 2 < NS && sim2 > bv) { bv = sim2; bs = s0 + 2; bn = n2; }
        if (s0 + 3 < NS && sim3 > bv) { bv = sim3; bs = s0 + 3; bn = n3; }
    }
    for (int o = 32; o; o >>= 1) {
        float v2 = __shfl_xor(bv, o, 64);
        int   i2 = __shfl_xor(bs, o, 64);
        float n2 = __shfl_xor(bn, o, 64);
        if (v2 > bv || (v2 == bv && i2 < bs)) { bv = v2; bs = i2; bn = n2; }
    }
    if (lane == 0) { wred[wid] = bv; wredi[wid] = bs; wredn[wid] = bn; }
    __syncthreads();
    if (tid == 0) {
        float v = wred[0]; int b = wredi[0]; float nn = wredn[0];
        for (int w = 1; w < 8; ++w)
            if (wred[w] > v || (wred[w] == v && wredi[w] < b)) {
                v = wred[w]; b = wredi[w]; nn = wredn[w];
            }
        s_theta = b;
        s_sc[1] = sqrtf(nn) * qn + EPSF;   // dn from carried nrm(theta)
    }
    __syncthreads();
    const int theta = s_theta;
    const float dn = s_sc[1];

    // softmax((x_opt*y/dn)/T); x_attn; y-count
    float xo = 0.f, z = 0.f;
    if (tid < DD) {
        xo = xpad[theta + tid];
        z = (xo * yr[tid] / dn) / TEMPER_F;
        float m = z;
        for (int o = 32; o; o >>= 1) { float w2 = __shfl_xor(m, o, 64); if (w2 > m) m = w2; }
        if (lane == 0) wred[wid] = m;
    }
    __syncthreads();
    if (tid == 0) {
        float m = wred[0];
        for (int w = 1; w < 6; ++w) if (wred[w] > m) m = wred[w];
        s_sc[2] = m;
    }
    __syncthreads();
    float ez = 0.f;
    if (tid < DD) {
        ez = expf(z - s_sc[2]);
        float p = ez;
        for (int o = 32; o; o >>= 1) p += __shfl_xor(p, o, 64);
        if (lane == 0) wred[wid] = p;
    }
    __syncthreads();
    if (tid == 0) {
        float s = 0.f;
        for (int w = 0; w < 6; ++w) s += wred[w];
        s_sc[3] = s;
    }
    __syncthreads();
    if (tid < DD) {
        xa[tid] = xo * (ez / s_sc[3]);
        int c = (yr[tid] != 0.f) ? 1 : 0;
        for (int o = 32; o; o >>= 1) c += __shfl_xor(c, o, 64);
        if (lane == 0) wredi[wid] = c;
    }
    __syncthreads();
    if (tid == 0) {
        int s = 0;
        for (int w = 0; w < 6; ++w) s += wredi[w];
        ycnt[row] = s;
    }
    if (tid < DD) {
        int sj = tid - (theta - (DD - 1));
        xe_g[row * DD + tid] = (sj >= 0 && sj < DD) ? xa[sj] : 0.f;
    }
}

// ---------------- 2) encoder GEMM: h = xe @ Wenc + benc ----------------
// grid 256 = 32 row-tiles(8 rows) x 8 col-tiles(128 cols); 256 threads.
// A-tile (8x384) in LDS (scalar broadcast reads); B float4 streamed (L1-reused
// across the 4 waves). ~4 FMA per b128 load.
__global__ __launch_bounds__(256) void enc_gemm(
    const float* __restrict__ xe_g, const float* __restrict__ Wenc,
    const float* __restrict__ benc, float* __restrict__ h_g)
{
    const int rt = blockIdx.x >> 3;        // 0..31
    const int ct = blockIdx.x & 7;         // 0..7
    const int tid = threadIdx.x;
    __shared__ __align__(16) float A[8 * DD];   // 12 KB
    {
        const float4* src = (const float4*)(xe_g + (size_t)rt * 8 * DD);
        float4* dst = (float4*)A;
        for (int i = tid; i < 8 * DD / 4; i += 256) dst[i] = src[i];
    }
    __syncthreads();
    const int r  = tid >> 5;               // 0..7
    const int c4 = (tid & 31) << 2;        // 0..124
    const int col = ct * 128 + c4;
    const float* wp = Wenc + col;
    const float* ar = A + r * DD;
    float4 acc = make_float4(0.f, 0.f, 0.f, 0.f);
#pragma unroll 4
    for (int j = 0; j < DD; ++j) {
        float a = ar[j];                   // 2 distinct addrs/wave -> free
        float4 w = *(const float4*)(wp + (size_t)j * HD);
        acc.x += a * w.x; acc.y += a * w.y;
        acc.z += a * w.z; acc.w += a * w.w;
    }
    float4 bb = *(const float4*)(benc + col);
    acc.x += bb.x; acc.y += bb.y; acc.z += bb.z; acc.w += bb.w;
    *(float4*)(h_g + (size_t)(rt * 8 + r) * HD + col) = acc;
}

// ---------------- 3) sort: register bitonic per row -> compact (v, off) ----------------
__global__ __launch_bounds__(512) void sort_kernel(
    const float* __restrict__ h_g, uint2* __restrict__ svo_g,
    int* __restrict__ fbs)
{
    const int row  = blockIdx.x;
    const int tid  = threadIdx.x;
    const int lane = tid & 63;

    __shared__ __align__(16) u64 skey[HD];    // LDS rounds only (j>=128)
    __shared__ int s_fb;

    // keys from coalesced float2 global reads (no strided LDS key scatter)
    const float* hrow = h_g + (size_t)row * HD;
    float2 hh = *(const float2*)(hrow + 2 * tid);
    u64 e0 = ((u64)(~flipf(hh.x)) << 32) | (u32)(2 * tid);
    u64 e1 = ((u64)(~flipf(hh.y)) << 32) | (u32)(2 * tid + 1);
    if (tid == 0) s_fb = HD;
    __syncthreads();

    // bitonic ascending on u64 key == (desc h value, asc index)
    for (int k = 2; k <= HD; k <<= 1) {
        const bool up = ((2 * tid) & k) == 0;
        for (int j = k >> 1; j > 0; j >>= 1) {
            if (j == 1) {
                bool sw = up ? (e0 > e1) : (e0 < e1);
                if (sw) { u64 t2 = e0; e0 = e1; e1 = t2; }
            } else if (j <= 64) {
                const int m = j >> 1;          // lane xor mask 1..32
                u64 p0 = shflx64(e0, m);
                u64 p1 = shflx64(e1, m);
                const bool takeMin = (((tid & m) == 0) == up);
                e0 = takeMin ? (e0 < p0 ? e0 : p0) : (e0 > p0 ? e0 : p0);
                e1 = takeMin ? (e1 < p1 ? e1 : p1) : (e1 > p1 ? e1 : p1);
            } else {                           // j in {128,256,512}: via LDS
                __syncthreads();               // WAR protection
                skey[2 * tid]     = e0;
                skey[2 * tid + 1] = e1;
                __syncthreads();
                const int tp = tid ^ (j >> 1);
                u64 p0 = skey[2 * tp];
                u64 p1 = skey[2 * tp + 1];
                const bool takeMin = (((tid & (j >> 1)) == 0) == up);
                e0 = takeMin ? (e0 < p0 ? e0 : p0) : (e0 > p0 ? e0 : p0);
                e1 = takeMin ? (e1 < p1 ? e1 : p1) : (e1 > p1 ? e1 : p1);
            }
        }
    }

    // write compact (value bits, Wdec byte-row offset) + first pos with v <= CUTF
    {
        float v0 = unflipf((u32)(e0 >> 32));
        float v1 = unflipf((u32)(e1 >> 32));
        svo_g[row * HD + 2 * tid]     = make_uint2(__float_as_uint(v0), ((u32)e0) * DD);
        svo_g[row * HD + 2 * tid + 1] = make_uint2(__float_as_uint(v1), ((u32)e1) * DD);
        int fbloc = HD;
        if (!(v1 > CUTF)) fbloc = 2 * tid + 1;
        if (!(v0 > CUTF)) fbloc = 2 * tid;
        for (int o = 32; o; o >>= 1) { int t2 = __shfl_xor(fbloc, o, 64); if (t2 < fbloc) fbloc = t2; }
        if (lane == 0) atomicMin(&s_fb, fbloc);
    }
    __syncthreads();
    if (tid == 0) fbs[row] = s_fb;
}

// ---------------- 4) decode: block per (row,k), 4-way rank striping ----------------
__global__ __launch_bounds__(384) void dec_kernel(
    const uint2* __restrict__ svo_g, const int* __restrict__ fbs,
    const float* __restrict__ Wdec, const float* __restrict__ bdec,
    const float* __restrict__ x, const float* __restrict__ y,
    float* __restrict__ out_xdis, float* __restrict__ lossp)
{
    const int row = blockIdx.x >> 2;
    const int k   = blockIdx.x & 3;
    const int tid = threadIdx.x;
    const int lane = tid & 63;
    const int wid  = tid >> 6;
    const int grp = tid / 96;            // rank stripe 0..3
    const int t   = tid - grp * 96;      // col group: cols 4t..4t+3

    __shared__ __align__(16) uint2 vo[CD];
    __shared__ __align__(16) float part[3][DD];
    __shared__ float wred[6];

    if (tid < CD) vo[tid] = svo_g[(size_t)row * HD + k * CD + tid];
    __syncthreads();
    const int fb = fbs[row];
    int n = (k == 0) ? CD : fb - k * CD;
    if (n < 0) n = 0; if (n > CD) n = CD;

    const float* wd = Wdec + 4 * t;
    float4 acc = make_float4(0.f, 0.f, 0.f, 0.f);
    int r = grp;
    for (; r + 13 <= n; r += 16) {       // 4 gathers in flight
#pragma unroll
        for (int q = 0; q < 4; ++q) {
            uint2 dv = vo[r + 4 * q];    // wave-broadcast
            float v = __uint_as_float(dv.x);
            float4 w = *(const float4*)(wd + dv.y);
            acc.x += v * w.x; acc.y += v * w.y;
            acc.z += v * w.z; acc.w += v * w.w;
        }
    }
    for (; r < n; r += 4) {
        uint2 dv = vo[r];
        float v = __uint_as_float(dv.x);
        float4 w = *(const float4*)(wd + dv.y);
        acc.x += v * w.x; acc.y += v * w.y;
        acc.z += v * w.z; acc.w += v * w.w;
    }
    if (grp) *(float4*)&part[grp - 1][4 * t] = acc;
    __syncthreads();

    float l = 0.f;
    if (grp == 0) {
        float4 p1 = *(const float4*)&part[0][4 * t];
        float4 p2 = *(const float4*)&part[1][4 * t];
        float4 p3 = *(const float4*)&part[2][4 * t];
        float4 bb = *(const float4*)&bdec[4 * t];
        acc.x += p1.x + p2.x + p3.x + bb.x;
        acc.y += p1.y + p2.y + p3.y + bb.y;
        acc.z += p1.z + p2.z + p3.z + bb.z;
        acc.w += p1.w + p2.w + p3.w + bb.w;
        *(float4*)&out_xdis[((size_t)k * NROWS + row) * DD + 4 * t] = acc;
        float4 xv = *(const float4*)&x[row * DD + 4 * t];
        float4 yv = *(const float4*)&y[row * DD + 4 * t];
        float e;
        e = acc.x - xv.x; if (yv.x != 0.f) l += e * e;
        e = acc.y - xv.y; if (yv.y != 0.f) l += e * e;
        e = acc.z - xv.z; if (yv.z != 0.f) l += e * e;
        e = acc.w - xv.w; if (yv.w != 0.f) l += e * e;
    }
    for (int o = 32; o; o >>= 1) l += __shfl_xor(l, o, 64);
    if (lane == 0) wred[wid] = l;
    __syncthreads();
    if (tid == 0) {
        float s = 0.f;
        for (int w = 0; w < 6; ++w) s += wred[w];
        lossp[row * NITER + k] = s;      // unique slot per block: no atomics
    }
}

// ---------------- 5) finalize: losses[k] = sum lossp / sum ycnt ----------------
__global__ __launch_bounds__(256) void finalize2(
    const float* __restrict__ lossp, const int* __restrict__ ycnt,
    float* __restrict__ losses)
{
    const int tid = threadIdx.x, lane = tid & 63, w = tid >> 6;
    __shared__ int ctot[4];
    int c = ycnt[tid];
    for (int o = 32; o; o >>= 1) c += __shfl_xor(c, o, 64);
    if (lane == 0) ctot[w] = c;
    __syncthreads();
    const int total = ctot[0] + ctot[1] + ctot[2] + ctot[3];
    float s = lossp[lane * NITER + w] + lossp[(lane + 64) * NITER + w]
            + lossp[(lane + 128) * NITER + w] + lossp[(lane + 192) * NITER + w];
    for (int o = 32; o; o >>= 1) s += __shfl_xor(s, o, 64);
    if (lane == 0) losses[w] = s / (float)total;
}

extern "C" void kernel_launch(void* const* d_in, const int* in_sizes, int n_in,
                              void* d_out, int out_size, void* d_ws, size_t ws_size,
                              hipStream_t stream) {
    const float* x    = (const float*)d_in[0];
    const float* y    = (const float*)d_in[1];
    const float* Wenc = (const float*)d_in[2];
    const float* benc = (const float*)d_in[3];
    const float* Wdec = (const float*)d_in[4];
    const float* bdec = (const float*)d_in[5];

    float* out  = (float*)d_out;
    float* loss = out + (out_size - NITER);

    // workspace (all regions fully written before read; 16B-aligned offsets)
    int*   ycnt  = (int*)d_ws;                           // 256 ints
    float* lossp = (float*)(ycnt + NROWS);               // 1024 floats
    float* xe_g  = lossp + NROWS * NITER;                // 256*384
    float* h_g   = xe_g + (size_t)NROWS * DD;            // 256*1024
    uint2* svo_g = (uint2*)(h_g + (size_t)NROWS * HD);   // 256*1024 uint2
    int*   fbs   = (int*)(svo_g + (size_t)NROWS * HD);   // 256 ints

    prep_kernel<<<NROWS, 512, 0, stream>>>(x, y, xe_g, ycnt);
    enc_gemm<<<256, 256, 0, stream>>>(xe_g, Wenc, benc, h_g);
    sort_kernel<<<NROWS, 512, 0, stream>>>(h_g, svo_g, fbs);
    dec_kernel<<<NROWS * NITER, 384, 0, stream>>>(svo_g, fbs, Wdec, bdec,
                                                  x, y, out, lossp);
    finalize2<<<1, 256, 0, stream>>>(lossp, ycnt, loss);
}

// Round 10
// 113.108 us; speedup vs baseline: 1.2931x; 1.2931x over previous
//
#include <hip/hip_runtime.h>
#include <math.h>

#define DD 384
#define HD 1024
#define CD 256
#define NS 765        // 2*DD-1 shifts
#define NITER 4
#define NROWS 256     // B*T
#define TEMPER_F 10.0f
#define EPSF 1e-6f
#define CUTF 1e-10f

typedef unsigned long long u64;
typedef unsigned int u32;

// monotone float->uint (ascending)
__device__ __forceinline__ u32 flipf(float f) {
    u32 u = __float_as_uint(f);
    return u ^ ((u32)((int)u >> 31) | 0x80000000u);
}
// inverse, where s = ~flip(v)
__device__ __forceinline__ float unflipf(u32 s) {
    u32 fl = ~s;
    u32 u = (fl & 0x80000000u) ? (fl ^ 0x80000000u) : ~fl;
    return __uint_as_float(u);
}
__device__ __forceinline__ u64 shflx64(u64 v, int m) {
    int lo = __shfl_xor((int)(u32)v, m, 64);
    int hi = __shfl_xor((int)(u32)(v >> 32), m, 64);
    return ((u64)(u32)hi << 32) | (u32)lo;
}

// One block per row: prep -> encoder -> register-bitonic sort -> decode.
__global__ __launch_bounds__(512) void fused_kernel(
    const float* __restrict__ x, const float* __restrict__ y,
    const float* __restrict__ Wenc, const float* __restrict__ benc,
    const float* __restrict__ Wdec, const float* __restrict__ bdec,
    float* __restrict__ out_xdis, float* __restrict__ lossp,
    int* __restrict__ ycnt)
{
    const int row  = blockIdx.x;
    const int tid  = threadIdx.x;
    const int lane = tid & 63;
    const int wid  = tid >> 6;

    __shared__ __align__(16) float xpad[1152];    // xfull(t), zero-padded
    __shared__ __align__(16) float yr[DD];
    __shared__ float xa[DD];
    __shared__ __align__(16) float xe_s[DD];
    __shared__ __align__(16) float hpart[HD];     // split-K partial, then final h
    __shared__ __align__(16) u64   skey[HD];      // sort LDS rounds (j>=128) only
    __shared__ __align__(16) uint2 dec2[HD];      // {bits(v), idx*DD}
    __shared__ float wred[8];
    __shared__ int   wredi[8];
    __shared__ float wredn[8];
    __shared__ float s_sc[4];                     // qn, dn, mx, sum
    __shared__ int   s_theta, s_fb;
    __shared__ float loss4[NITER];

    const float* xrow = x + row * DD;
    const float* yrow = y + row * DD;

    // xfull(t) = x[t-383] for t in [383,767), else 0
    for (int i = tid; i < 1152; i += 512)
        xpad[i] = (i >= DD - 1 && i < 2 * DD - 1) ? xrow[i - (DD - 1)] : 0.f;
    if (tid < DD) yr[tid] = yrow[tid];
    __syncthreads();

    // ---- qn = ||y||  (+ y-count folded into the same round) ----
    if (tid < DD) {
        float p = yr[tid] * yr[tid];
        int   c = (yr[tid] != 0.f) ? 1 : 0;
        for (int o = 32; o; o >>= 1) {
            p += __shfl_xor(p, o, 64);
            c += __shfl_xor(c, o, 64);
        }
        if (lane == 0) { wred[wid] = p; wredi[wid] = c; }
    }
    __syncthreads();
    if (tid == 0) {
        float s = 0.f; int c = 0;
        for (int w = 0; w < 6; ++w) { s += wred[w]; c += wredi[w]; }
        s_sc[0] = sqrtf(s);
        ycnt[row] = c;
    }
    __syncthreads();
    const float qn = s_sc[0];

    // ---- sim argmax: threads 0..191, 4 consecutive shifts each, sliding window ----
    float bv = -INFINITY; int bs = 0x7fffffff; float bn = 0.f;
    if (tid < 192) {
        const float4* xp4 = (const float4*)xpad;
        const float4* yp4 = (const float4*)yr;
        float4 A = xp4[tid];
        const float f0 = A.x * A.x, f1 = A.y * A.y, f2 = A.z * A.z;
        float d0 = 0.f, d1 = 0.f, d2 = 0.f, d3 = 0.f, n0 = 0.f;
#pragma unroll 4
        for (int jc = 0; jc < 96; ++jc) {
            float4 B = xp4[tid + jc + 1];
            float4 Y = yp4[jc];
            d0 += A.x * Y.x; d0 += A.y * Y.y; d0 += A.z * Y.z; d0 += A.w * Y.w;
            d1 += A.y * Y.x; d1 += A.z * Y.y; d1 += A.w * Y.z; d1 += B.x * Y.w;
            d2 += A.z * Y.x; d2 += A.w * Y.y; d2 += B.x * Y.z; d2 += B.y * Y.w;
            d3 += A.w * Y.x; d3 += B.x * Y.y; d3 += B.y * Y.z; d3 += B.z * Y.w;
            n0 += A.x * A.x; n0 += A.y * A.y; n0 += A.z * A.z; n0 += A.w * A.w;
            A = B;
        }
        const float n1 = n0 - f0 + A.x * A.x;
        const float n2 = n1 - f1 + A.y * A.y;
        const float n3 = n2 - f2 + A.z * A.z;
        const int s0 = 4 * tid;
        float sim0 = d0 / (qn * sqrtf(n0) + EPSF);
        float sim1 = d1 / (qn * sqrtf(n1) + EPSF);
        float sim2 = d2 / (qn * sqrtf(n2) + EPSF);
        float sim3 = d3 / (qn * sqrtf(n3) + EPSF);
        bv = sim0; bs = s0; bn = n0;
        if (s0 + 1 < NS && sim1 > bv) { bv = sim1; bs = s0 + 1; bn = n1; }
        if (s0 + 2 < NS && sim2 > bv) { bv = sim2; bs = s0 + 2; bn = n2; }
        if (s0 + 3 < NS && sim3 > bv) { bv = sim3; bs = s0 + 3; bn = n3; }
    }
    for (int o = 32; o; o >>= 1) {
        float v2 = __shfl_xor(bv, o, 64);
        int   i2 = __shfl_xor(bs, o, 64);
        float n2 = __shfl_xor(bn, o, 64);
        if (v2 > bv || (v2 == bv && i2 < bs)) { bv = v2; bs = i2; bn = n2; }
    }
    if (lane == 0) { wred[wid] = bv; wredi[wid] = bs; wredn[wid] = bn; }
    __syncthreads();
    if (tid == 0) {
        float v = wred[0]; int b = wredi[0]; float nn = wredn[0];
        for (int w = 1; w < 8; ++w)
            if (wred[w] > v || (wred[w] == v && wredi[w] < b)) {
                v = wred[w]; b = wredi[w]; nn = wredn[w];
            }
        s_theta = b;
        s_sc[1] = sqrtf(nn) * qn + EPSF;      // dn from carried nrm(theta)
    }
    __syncthreads();
    const int theta = s_theta;
    const float dn = s_sc[1];

    // ---- softmax((x_opt*y/dn)/T); x_attn ----
    float xo = 0.f, z = 0.f;
    if (tid < DD) {
        xo = xpad[theta + tid];
        z = (xo * yr[tid] / dn) / TEMPER_F;
        float m = z;
        for (int o = 32; o; o >>= 1) { float w2 = __shfl_xor(m, o, 64); if (w2 > m) m = w2; }
        if (lane == 0) wred[wid] = m;
    }
    __syncthreads();
    if (tid == 0) {
        float m = wred[0];
        for (int w = 1; w < 6; ++w) if (wred[w] > m) m = wred[w];
        s_sc[2] = m;
    }
    __syncthreads();
    float ez = 0.f;
    if (tid < DD) {
        ez = expf(z - s_sc[2]);
        float p = ez;
        for (int o = 32; o; o >>= 1) p += __shfl_xor(p, o, 64);
        if (lane == 0) wred[wid] = p;
    }
    __syncthreads();
    if (tid == 0) {
        float s = 0.f;
        for (int w = 0; w < 6; ++w) s += wred[w];
        s_sc[3] = s;
    }
    __syncthreads();
    if (tid < DD) xa[tid] = xo * (ez / s_sc[3]);
    __syncthreads();
    if (tid < DD) {
        int sj = tid - (theta - (DD - 1));
        xe_s[tid] = (sj >= 0 && sj < DD) ? xa[sj] : 0.f;
    }
    __syncthreads();

    // ---- encoder: split-K float4 GEMV. tid<256: j in [0,192); tid>=256: [192,384) ----
    const int c4 = tid & 255;
    const int jh = tid >> 8;
    float4 acc = make_float4(0.f, 0.f, 0.f, 0.f);
    {
        const float* wbase = Wenc + (size_t)(jh * 192) * HD + 4 * c4;
        const float* xb = xe_s + jh * 192;
#pragma unroll 8
        for (int j = 0; j < 192; ++j) {
            float xv = xb[j];                 // broadcast
            float4 w = *(const float4*)(wbase + (size_t)j * HD);
            acc.x += xv * w.x; acc.y += xv * w.y;
            acc.z += xv * w.z; acc.w += xv * w.w;
        }
    }
    if (jh == 1) *(float4*)&hpart[4 * c4] = acc;
    if (tid == 0) s_fb = HD;
    if (tid < NITER) loss4[tid] = 0.f;
    __syncthreads();
    if (jh == 0) {
        // same thread reads and rewrites its own slot: in-place final h
        float4 hp = *(const float4*)&hpart[4 * c4];
        float4 bb = *(const float4*)&benc[4 * c4];
        hp.x += acc.x + bb.x;
        hp.y += acc.y + bb.y;
        hp.z += acc.z + bb.z;
        hp.w += acc.w + bb.w;
        *(float4*)&hpart[4 * c4] = hp;
    }
    __syncthreads();

    // ---- build keys from contiguous float2 reads (no strided u64 scatter) ----
    float2 hh = *(const float2*)&hpart[2 * tid];
    u64 e0 = ((u64)(~flipf(hh.x)) << 32) | (u32)(2 * tid);
    u64 e1 = ((u64)(~flipf(hh.y)) << 32) | (u32)(2 * tid + 1);

    // ---- register bitonic sort: thread t owns positions 2t, 2t+1 ----
    // ascending u64 key == descending h value, ascending index.
    for (int k = 2; k <= HD; k <<= 1) {
        const bool up = ((2 * tid) & k) == 0;
        for (int j = k >> 1; j > 0; j >>= 1) {
            if (j == 1) {
                bool sw = up ? (e0 > e1) : (e0 < e1);
                if (sw) { u64 t2 = e0; e0 = e1; e1 = t2; }
            } else if (j <= 64) {
                const int m = j >> 1;          // lane xor mask 1..32
                u64 p0 = shflx64(e0, m);
                u64 p1 = shflx64(e1, m);
                const bool takeMin = (((tid & m) == 0) == up);
                e0 = takeMin ? (e0 < p0 ? e0 : p0) : (e0 > p0 ? e0 : p0);
                e1 = takeMin ? (e1 < p1 ? e1 : p1) : (e1 > p1 ? e1 : p1);
            } else {                           // j in {128,256,512}: via LDS
                __syncthreads();               // WAR protection
                skey[2 * tid]     = e0;
                skey[2 * tid + 1] = e1;
                __syncthreads();
                const int tp = tid ^ (j >> 1);
                u64 p0 = skey[2 * tp];
                u64 p1 = skey[2 * tp + 1];
                const bool takeMin = (((tid & (j >> 1)) == 0) == up);
                e0 = takeMin ? (e0 < p0 ? e0 : p0) : (e0 > p0 ? e0 : p0);
                e1 = takeMin ? (e1 < p1 ? e1 : p1) : (e1 > p1 ? e1 : p1);
            }
        }
    }

    // ---- unpack from registers + first position with v <= CUTF ----
    {
        float v0 = unflipf((u32)(e0 >> 32));
        float v1 = unflipf((u32)(e1 >> 32));
        dec2[2 * tid]     = make_uint2(__float_as_uint(v0), ((u32)e0) * DD);
        dec2[2 * tid + 1] = make_uint2(__float_as_uint(v1), ((u32)e1) * DD);
        int fbloc = HD;
        if (!(v1 > CUTF)) fbloc = 2 * tid + 1;
        if (!(v0 > CUTF)) fbloc = 2 * tid;
        for (int o = 32; o; o >>= 1) { int t2 = __shfl_xor(fbloc, o, 64); if (t2 < fbloc) fbloc = t2; }
        if (lane == 0) atomicMin(&s_fb, fbloc);
    }
    __syncthreads();
    const int fb = s_fb;

    // ---- decode: 4 groups of 128 threads (k wave-uniform), 4 d-cols/thread,
    //      unroll 8 -> 8 float4 gathers in flight ----
    {
        const int k = tid >> 7;
        const int g = tid & 127;
        const bool active = (g < 96);
        int n = 0;
        if (active) {
            n = (k == 0) ? CD : fb - k * CD;
            if (n < 0) n = 0; if (n > CD) n = CD;
        }
        float4 oacc = make_float4(0.f, 0.f, 0.f, 0.f);
        if (active) oacc = *(const float4*)&bdec[4 * g];
        const float* wd = Wdec + 4 * g;
        const int base = k * CD;
        int r = 0;
        for (; r + 8 <= n; r += 8) {
#pragma unroll
            for (int q = 0; q < 8; q += 2) {
                uint4 dv = *(const uint4*)&dec2[base + r + q];   // 2 entries, broadcast
                float v0 = __uint_as_float(dv.x);
                float4 w0 = *(const float4*)(wd + dv.y);
                float v1 = __uint_as_float(dv.z);
                float4 w1 = *(const float4*)(wd + dv.w);
                oacc.x += v0 * w0.x; oacc.y += v0 * w0.y;
                oacc.z += v0 * w0.z; oacc.w += v0 * w0.w;
                oacc.x += v1 * w1.x; oacc.y += v1 * w1.y;
                oacc.z += v1 * w1.z; oacc.w += v1 * w1.w;
            }
        }
        for (; r < n; ++r) {
            uint2 dv = dec2[base + r];
            float v0 = __uint_as_float(dv.x);
            float4 w0 = *(const float4*)(wd + dv.y);
            oacc.x += v0 * w0.x; oacc.y += v0 * w0.y;
            oacc.z += v0 * w0.z; oacc.w += v0 * w0.w;
        }
        float l = 0.f;
        if (active) {
            *(float4*)&out_xdis[((size_t)k * NROWS + row) * DD + 4 * g] = oacc;
            float4 xv = *(const float4*)&xrow[4 * g];
            float4 yv = *(const float4*)&yr[4 * g];
            float e;
            e = oacc.x - xv.x; if (yv.x != 0.f) l += e * e;
            e = oacc.y - xv.y; if (yv.y != 0.f) l += e * e;
            e = oacc.z - xv.z; if (yv.z != 0.f) l += e * e;
            e = oacc.w - xv.w; if (yv.w != 0.f) l += e * e;
        }
        for (int o = 32; o; o >>= 1) l += __shfl_xor(l, o, 64);
        if (lane == 0) atomicAdd(&loss4[k], l);
    }
    __syncthreads();
    if (tid < NITER) lossp[row * NITER + tid] = loss4[tid];
}

// ---- finalize: losses[k] = sum_rows lossp / sum_rows ycnt ----
__global__ __launch_bounds__(256) void finalize2(
    const float* __restrict__ lossp, const int* __restrict__ ycnt,
    float* __restrict__ losses)
{
    const int tid = threadIdx.x, lane = tid & 63, w = tid >> 6;
    __shared__ int ctot[4];
    int c = ycnt[tid];
    for (int o = 32; o; o >>= 1) c += __shfl_xor(c, o, 64);
    if (lane == 0) ctot[w] = c;
    __syncthreads();
    const int total = ctot[0] + ctot[1] + ctot[2] + ctot[3];
    float s = lossp[lane * NITER + w] + lossp[(lane + 64) * NITER + w]
            + lossp[(lane + 128) * NITER + w] + lossp[(lane + 192) * NITER + w];
    for (int o = 32; o; o >>= 1) s += __shfl_xor(s, o, 64);
    if (lane == 0) losses[w] = s / (float)total;
}

extern "C" void kernel_launch(void* const* d_in, const int* in_sizes, int n_in,
                              void* d_out, int out_size, void* d_ws, size_t ws_size,
                              hipStream_t stream) {
    const float* x    = (const float*)d_in[0];
    const float* y    = (const float*)d_in[1];
    const float* Wenc = (const float*)d_in[2];
    const float* benc = (const float*)d_in[3];
    const float* Wdec = (const float*)d_in[4];
    const float* bdec = (const float*)d_in[5];

    float* out  = (float*)d_out;
    float* loss = out + (out_size - NITER);

    float* lossp = (float*)d_ws;                       // 256*4 floats, fully written
    int*   ycnt  = (int*)(lossp + NROWS * NITER);      // 256 ints, fully written

    fused_kernel<<<NROWS, 512, 0, stream>>>(x, y, Wenc, benc, Wdec, bdec,
                                            out, lossp, ycnt);
    finalize2<<<1, 256, 0, stream>>>(lossp, ycnt, loss);
}